// Round 9
// baseline (518.382 us; speedup 1.0000x reference)
//
#include <hip/hip_runtime.h>

// GAT 2-layer + mean-pool + MLP. bf16 internal features, MFMA GEMMs (hi/lo split W),
// atomic-free binned CSR build.
// Round 9: agg2 reworked to 16-lane/4-edge groups (R8's 8-edge granularity padded
// deg~17 chunks to 24 -> 40% wasted iterations; 4-granularity wastes 16%). agg1 gets
// unroll 4 (single-chunk nodes: deeper load queue). convW fused to one launch.

#define LRELU(x) fmaxf((x), 0.2f * (x))

using bf16x8 = __attribute__((ext_vector_type(8))) short;
using f32x16 = __attribute__((ext_vector_type(16))) float;

#define NSB 256  // scatter blocks (fixed; cntmat is [NBK][NSB])

__device__ inline unsigned short f2bf(float f) {
  unsigned u = __builtin_bit_cast(unsigned, f);
  return (unsigned short)((u + 0x7fffu + ((u >> 16) & 1u)) >> 16);  // RNE
}
__device__ inline float bf2f(unsigned short h) {
  return __builtin_bit_cast(float, (unsigned)h << 16);
}
__device__ inline float bfLO(unsigned v) { return __builtin_bit_cast(float, v << 16); }
__device__ inline float bfHI(unsigned v) { return __builtin_bit_cast(float, v & 0xffff0000u); }
__device__ inline unsigned packbf(float a, float b) {
  return (unsigned)f2bf(a) | ((unsigned)f2bf(b) << 16);
}

// wave-synchronous LDS publish: all lanes' ds_writes drained before any ds_read.
__device__ inline void wave_lds_fence() {
  __builtin_amdgcn_wave_barrier();
  __builtin_amdgcn_s_waitcnt(0xc07f);  // lgkmcnt(0)
  __builtin_amdgcn_wave_barrier();
}

// ---------------- binned CSR build ----------------
// bucket b = dst >> 8 covers dsts [b*256, b*256+256). NBK = ceil(N/256) <= 512.

__global__ __launch_bounds__(256) void k_hist2(const int* __restrict__ dst, int E, int chunk,
                                               int NBK, int* __restrict__ cntmat) {
  __shared__ int lh[512];
  int b = blockIdx.x, t = threadIdx.x;
  for (int i = t; i < NBK; i += 256) lh[i] = 0;
  __syncthreads();
  int beg = b * chunk, end = min(E, beg + chunk);
  for (int e = beg + t; e < end; e += 256) atomicAdd(&lh[dst[e] >> 8], 1);
  __syncthreads();
  for (int i = t; i < NBK; i += 256) cntmat[i * NSB + b] = lh[i];
}

__global__ __launch_bounds__(256) void k_rowscan(int* __restrict__ cntmat,
                                                 int* __restrict__ bucket_tot) {
  int k = blockIdx.x, t = threadIdx.x;
  __shared__ int sc[256];
  int v = cntmat[k * NSB + t];
  sc[t] = v;
  __syncthreads();
  for (int off = 1; off < 256; off <<= 1) {
    int add = (t >= off) ? sc[t - off] : 0;
    __syncthreads();
    sc[t] += add;
    __syncthreads();
  }
  cntmat[k * NSB + t] = sc[t] - v;
  if (t == 255) bucket_tot[k] = sc[t];
}

__global__ __launch_bounds__(512) void k_bscan(const int* __restrict__ bucket_tot, int NBK,
                                               int* __restrict__ bucket_off,
                                               int* __restrict__ row_off, int N, int E) {
  __shared__ int sc[512];
  int t = threadIdx.x;
  int v = (t < NBK) ? bucket_tot[t] : 0;
  sc[t] = v;
  __syncthreads();
  for (int off = 1; off < 512; off <<= 1) {
    int add = (t >= off) ? sc[t - off] : 0;
    __syncthreads();
    sc[t] += add;
    __syncthreads();
  }
  int excl = sc[t] - v;
  if (t < NBK) {
    bucket_off[t] = excl;
    if (t == NBK - 1) bucket_off[NBK] = excl + v;
  }
  if (t == 0) row_off[N] = E + N;
}

__global__ __launch_bounds__(256) void k_scatter2(const int* __restrict__ src,
                                                  const int* __restrict__ dst, int E, int chunk,
                                                  int NBK, const int* __restrict__ bucket_off,
                                                  const int* __restrict__ cntmat,
                                                  int* __restrict__ pairs) {
  __shared__ int base[512];
  __shared__ int cur[512];
  int b = blockIdx.x, t = threadIdx.x;
  for (int i = t; i < NBK; i += 256) {
    base[i] = bucket_off[i] + cntmat[i * NSB + b];
    cur[i] = 0;
  }
  __syncthreads();
  int beg = b * chunk, end = min(E, beg + chunk);
  for (int e = beg + t; e < end; e += 256) {
    int s = src[e], d = dst[e];
    int k = d >> 8;
    int loc = atomicAdd(&cur[k], 1);  // LDS atomic: block-private
    pairs[base[k] + loc] = (s << 8) | (d & 255);
  }
}

#define BBUILD_CAP 8448
__global__ __launch_bounds__(256) void k_bbuild(const int* __restrict__ pairs,
                                                const int* __restrict__ bucket_off,
                                                int N, int* __restrict__ row_off,
                                                int* __restrict__ col) {
  int b = blockIdx.x;
  int t = threadIdx.x;
  int base_d = b * 256;
  int nd = N - base_d;
  if (nd > 256) nd = 256;
  int pbeg = bucket_off[b], pend = bucket_off[b + 1];
  int cntb = pend - pbeg;
  int colbase = pbeg + base_d;

  __shared__ int hist[256];
  __shared__ int scn[256];
  __shared__ int cur[256];
  __shared__ int colL[BBUILD_CAP];
  hist[t] = 0;
  __syncthreads();
  for (int p = pbeg + t; p < pend; p += 256) atomicAdd(&hist[pairs[p] & 255], 1);
  __syncthreads();
  int v = (t < nd) ? hist[t] + 1 : 0;
  scn[t] = v;
  __syncthreads();
  for (int off = 1; off < 256; off <<= 1) {
    int add = (t >= off) ? scn[t - off] : 0;
    __syncthreads();
    scn[t] += add;
    __syncthreads();
  }
  int excl = scn[t] - v;
  if (t < nd) row_off[base_d + t] = colbase + excl;
  int total = cntb + nd;
  if (total <= BBUILD_CAP) {
    cur[t] = excl;
    if (t < nd) colL[excl + hist[t]] = base_d + t;
    __syncthreads();
    for (int p = pbeg + t; p < pend; p += 256) {
      int w = pairs[p];
      int lp = atomicAdd(&cur[w & 255], 1);
      colL[lp] = w >> 8;
    }
    __syncthreads();
    for (int i = t; i < total; i += 256) col[colbase + i] = colL[i];
  } else {
    cur[t] = excl;
    if (t < nd) col[colbase + excl + hist[t]] = base_d + t;
    __syncthreads();
    for (int p = pbeg + t; p < pend; p += 256) {
      int w = pairs[p];
      int lp = atomicAdd(&cur[w & 255], 1);
      col[colbase + lp] = w >> 8;
    }
  }
}

// ---------------- weight conversion (both layers, one launch) ----------------

__global__ __launch_bounds__(256) void k_convW(const float* __restrict__ W1,
                                               const float* __restrict__ W2,
                                               unsigned short* __restrict__ T1h,
                                               unsigned short* __restrict__ T1l,
                                               unsigned short* __restrict__ T2h,
                                               unsigned short* __restrict__ T2l) {
  const int E1 = 128 * 192;  // W1: K=128, N=192
  const int E2 = 192 * 96;   // W2: K=192, N=96
  int idx = blockIdx.x * 256 + threadIdx.x;
  if (idx < E1) {
    int k = idx / 192, n = idx - k * 192;
    float w = W1[idx];
    unsigned short hi = f2bf(w);
    unsigned short lo = f2bf(w - bf2f(hi));
    T1h[n * 128 + k] = hi;
    T1l[n * 128 + k] = lo;
  } else if (idx < E1 + E2) {
    int i2 = idx - E1;
    int k = i2 / 96, n = i2 - k * 96;
    float w = W2[i2];
    unsigned short hi = f2bf(w);
    unsigned short lo = f2bf(w - bf2f(hi));
    T2h[n * 192 + k] = hi;
    T2l[n * 192 + k] = lo;
  }
}

// ---------------- MFMA GEMM: C[M,N](bf16) = A[M,K] @ (Bh+Bl) ----------------

template <int K, int N, bool A_BF16>
__global__ __launch_bounds__(256) void k_gemm_mfma(const void* __restrict__ Ap,
                                                   const unsigned short* __restrict__ Bh,
                                                   const unsigned short* __restrict__ Bl,
                                                   unsigned short* __restrict__ C, int M) {
  constexpr int NT = N / 32;
  __shared__ unsigned short As[128 * 40];
  __shared__ unsigned short Bhs[N * 40];
  __shared__ unsigned short Bls[N * 40];
  int tid = threadIdx.x;
  int wave = tid >> 6, lane = tid & 63;
  int bm = blockIdx.x * 128;

  f32x16 acc[NT];
#pragma unroll
  for (int t = 0; t < NT; ++t)
#pragma unroll
    for (int i = 0; i < 16; ++i) acc[t][i] = 0.f;

  for (int k0 = 0; k0 < K; k0 += 32) {
#pragma unroll
    for (int i = 0; i < 2; ++i) {
      int unit = tid + i * 256;
      int r = unit >> 2, u = unit & 3;
      int gr = bm + r;
      uint4 o = make_uint4(0, 0, 0, 0);
      if (gr < M) {
        if (A_BF16) {
          o = *(const uint4*)((const unsigned short*)Ap + (size_t)gr * K + k0 + u * 8);
        } else {
          const float* af = (const float*)Ap + (size_t)gr * K + k0 + u * 8;
          float4 v0 = *(const float4*)af;
          float4 v1 = *(const float4*)(af + 4);
          o.x = (unsigned)f2bf(v0.x) | ((unsigned)f2bf(v0.y) << 16);
          o.y = (unsigned)f2bf(v0.z) | ((unsigned)f2bf(v0.w) << 16);
          o.z = (unsigned)f2bf(v1.x) | ((unsigned)f2bf(v1.y) << 16);
          o.w = (unsigned)f2bf(v1.z) | ((unsigned)f2bf(v1.w) << 16);
        }
      }
      *(uint4*)&As[r * 40 + u * 8] = o;
    }
    for (int unit = tid; unit < N * 4; unit += 256) {
      int n = unit >> 2, u = unit & 3;
      *(uint4*)&Bhs[n * 40 + u * 8] = *(const uint4*)&Bh[n * K + k0 + u * 8];
      *(uint4*)&Bls[n * 40 + u * 8] = *(const uint4*)&Bl[n * K + k0 + u * 8];
    }
    __syncthreads();

    int arow = wave * 32 + (lane & 31);
    int fo = (lane >> 5) * 8;
#pragma unroll
    for (int s = 0; s < 2; ++s) {
      bf16x8 af = *(const bf16x8*)&As[arow * 40 + s * 16 + fo];
#pragma unroll
      for (int t = 0; t < NT; ++t) {
        bf16x8 bh = *(const bf16x8*)&Bhs[(t * 32 + (lane & 31)) * 40 + s * 16 + fo];
        bf16x8 bl = *(const bf16x8*)&Bls[(t * 32 + (lane & 31)) * 40 + s * 16 + fo];
        acc[t] = __builtin_amdgcn_mfma_f32_32x32x16_bf16(af, bh, acc[t], 0, 0, 0);
        acc[t] = __builtin_amdgcn_mfma_f32_32x32x16_bf16(af, bl, acc[t], 0, 0, 0);
      }
    }
    __syncthreads();
  }

#pragma unroll
  for (int t = 0; t < NT; ++t) {
    int col = t * 32 + (lane & 31);
#pragma unroll
    for (int r = 0; r < 16; ++r) {
      int row = wave * 32 + (r & 3) + 8 * (r >> 2) + 4 * (lane >> 5);
      int gr = bm + row;
      if (gr < M) C[(size_t)gr * N + col] = f2bf(acc[t][r]);
    }
  }
}

// ---------------- attention coefficients (h in bf16, dword loads) ----------------

__global__ __launch_bounds__(256) void k_coef1(const unsigned short* __restrict__ h,
                                               const float* __restrict__ a_src,
                                               const float* __restrict__ a_dst,
                                               float* __restrict__ asrc,
                                               float* __restrict__ adst, int N) {
  int node = blockIdx.x * 4 + (threadIdx.x >> 6);
  if (node >= N) return;
  int m = threadIdx.x & 63;
  const unsigned* hp = (const unsigned*)h + (size_t)node * 96;
  unsigned va = hp[m];
  float x0 = bfLO(va), x1 = bfHI(va);
  float2 as = *(const float2*)&a_src[2 * m];
  float2 ad = *(const float2*)&a_dst[2 * m];
  float pas = x0 * as.x + x1 * as.y;
  float pad = x0 * ad.x + x1 * ad.y;
  int ha = m / 24;
  float pbs = 0.f, pbd = 0.f;
  int hb = (m < 8) ? 2 : 3;
  if (m < 32) {
    unsigned vb = hp[64 + m];
    float y0 = bfLO(vb), y1 = bfHI(vb);
    float2 bs = *(const float2*)&a_src[128 + 2 * m];
    float2 bd = *(const float2*)&a_dst[128 + 2 * m];
    pbs = y0 * bs.x + y1 * bs.y;
    pbd = y0 * bd.x + y1 * bd.y;
  }
  float4 cs, cd;
  cs.x = (ha == 0) ? pas : 0.f;
  cs.y = (ha == 1) ? pas : 0.f;
  cs.z = ((ha == 2) ? pas : 0.f) + ((hb == 2) ? pbs : 0.f);
  cs.w = (hb == 3) ? pbs : 0.f;
  cd.x = (ha == 0) ? pad : 0.f;
  cd.y = (ha == 1) ? pad : 0.f;
  cd.z = ((ha == 2) ? pad : 0.f) + ((hb == 2) ? pbd : 0.f);
  cd.w = (hb == 3) ? pbd : 0.f;
#pragma unroll
  for (int off = 1; off < 64; off <<= 1) {
    cs.x += __shfl_xor(cs.x, off);
    cs.y += __shfl_xor(cs.y, off);
    cs.z += __shfl_xor(cs.z, off);
    cs.w += __shfl_xor(cs.w, off);
    cd.x += __shfl_xor(cd.x, off);
    cd.y += __shfl_xor(cd.y, off);
    cd.z += __shfl_xor(cd.z, off);
    cd.w += __shfl_xor(cd.w, off);
  }
  if (m == 0) {
    *(float4*)&asrc[node * 4] = cs;
    *(float4*)&adst[node * 4] = cd;
  }
}

__global__ __launch_bounds__(256) void k_coef2(const unsigned short* __restrict__ h,
                                               const float* __restrict__ a_src,
                                               const float* __restrict__ a_dst,
                                               float* __restrict__ asrc,
                                               float* __restrict__ adst, int N) {
  int node = blockIdx.x * 4 + (threadIdx.x >> 6);
  if (node >= N) return;
  int m = threadIdx.x & 63;
  float ps = 0.f, pd = 0.f;
  if (m < 48) {
    unsigned v = ((const unsigned*)h)[(size_t)node * 48 + m];
    float x0 = bfLO(v), x1 = bfHI(v);
    float2 as = *(const float2*)&a_src[2 * m];
    float2 ad = *(const float2*)&a_dst[2 * m];
    ps = x0 * as.x + x1 * as.y;
    pd = x0 * ad.x + x1 * ad.y;
  }
#pragma unroll
  for (int off = 1; off < 64; off <<= 1) {
    ps += __shfl_xor(ps, off);
    pd += __shfl_xor(pd, off);
  }
  if (m == 0) {
    asrc[node] = ps;
    adst[node] = pd;
  }
}

// ---------------- aggregation: quarter-wave gather, LDS weight broadcast ----------------

// layer1: 192 ch (96 dwords), 4 heads. Wave per node; quarter q handles staged edge
// j+q; lane m=lane&15 owns dwords {4m..4m+3} (uint4, head m/6) and {64+2m,65+2m}
// (uint2, head m<4?2:3). 4 edges per iteration. Padded staged entries have w=0.
__global__ __launch_bounds__(256) void k_agg1(const unsigned short* __restrict__ h,
                                              const float* __restrict__ asrc,
                                              const float* __restrict__ adst,
                                              const int* __restrict__ row_off,
                                              const int* __restrict__ col,
                                              const float* __restrict__ b1,
                                              unsigned short* __restrict__ out, int N) {
  __shared__ int sL[4][64];
  __shared__ float wL[4][64][4];
  int wid = threadIdx.x >> 6;
  int node = blockIdx.x * 4 + wid;
  if (node >= N) return;
  int lane = threadIdx.x & 63;
  int q = lane >> 4;
  int m = lane & 15;
  int hA = m / 6;            // head of dwords 4m..4m+3 (ch 8m..8m+7)
  int hB = (m < 4) ? 2 : 3;  // head of dwords 64+2m (ch 128+4m..131+4m)
  int beg = __builtin_amdgcn_readfirstlane(row_off[node]);
  int end = __builtin_amdgcn_readfirstlane(row_off[node + 1]);
  float4 ad = *(const float4*)&adst[node * 4];
  float accA0 = 0, accA1 = 0, accA2 = 0, accA3 = 0;
  float accA4 = 0, accA5 = 0, accA6 = 0, accA7 = 0;
  float accB0 = 0, accB1 = 0, accB2 = 0, accB3 = 0;
  float da = 0.f, db = 0.f;
  const unsigned* h32 = (const unsigned*)h;
  for (int base = beg; base < end; base += 64) {
    int cnt = end - base;
    if (cnt > 64) cnt = 64;
    int s = 0;
    float w0 = 0.f, w1 = 0.f, w2 = 0.f, w3 = 0.f;
    if (lane < cnt) {
      s = col[base + lane];
      float4 as = *(const float4*)&asrc[s * 4];
      w0 = __expf(LRELU(as.x + ad.x));
      w1 = __expf(LRELU(as.y + ad.y));
      w2 = __expf(LRELU(as.z + ad.z));
      w3 = __expf(LRELU(as.w + ad.w));
    }
    sL[wid][lane] = s;
    *(float4*)&wL[wid][lane][0] = make_float4(w0, w1, w2, w3);
    wave_lds_fence();
    int jmax = (cnt + 3) & ~3;
#pragma unroll 4
    for (int j = 0; j < jmax; j += 4) {
      int je = j + q;
      int sj = sL[wid][je];
      float wa = wL[wid][je][hA];
      float wb = wL[wid][je][hB];
      const unsigned* hp = h32 + (size_t)sj * 96;
      uint4 va = *(const uint4*)(hp + 4 * m);
      uint2 vb = *(const uint2*)(hp + 64 + 2 * m);
      da += wa;
      db += wb;
      accA0 += wa * bfLO(va.x);
      accA1 += wa * bfHI(va.x);
      accA2 += wa * bfLO(va.y);
      accA3 += wa * bfHI(va.y);
      accA4 += wa * bfLO(va.z);
      accA5 += wa * bfHI(va.z);
      accA6 += wa * bfLO(va.w);
      accA7 += wa * bfHI(va.w);
      accB0 += wb * bfLO(vb.x);
      accB1 += wb * bfHI(vb.x);
      accB2 += wb * bfLO(vb.y);
      accB3 += wb * bfHI(vb.y);
    }
    __builtin_amdgcn_wave_barrier();  // reads done before next chunk overwrites
  }
  // combine the four quarters
#define RED2(x) x += __shfl_xor(x, 16); x += __shfl_xor(x, 32)
  RED2(da); RED2(db);
  RED2(accA0); RED2(accA1); RED2(accA2); RED2(accA3);
  RED2(accA4); RED2(accA5); RED2(accA6); RED2(accA7);
  RED2(accB0); RED2(accB1); RED2(accB2); RED2(accB3);
#undef RED2
  if (q == 0) {
    float ra = 1.f / da, rb = 1.f / db;
    float4 biA0 = *(const float4*)&b1[8 * m];
    float4 biA1 = *(const float4*)&b1[8 * m + 4];
    float4 biB = *(const float4*)&b1[128 + 4 * m];
    unsigned* op = (unsigned*)(out + (size_t)node * 192);
    uint4 pa;
    pa.x = packbf(fmaxf(accA0 * ra + biA0.x, 0.f), fmaxf(accA1 * ra + biA0.y, 0.f));
    pa.y = packbf(fmaxf(accA2 * ra + biA0.z, 0.f), fmaxf(accA3 * ra + biA0.w, 0.f));
    pa.z = packbf(fmaxf(accA4 * ra + biA1.x, 0.f), fmaxf(accA5 * ra + biA1.y, 0.f));
    pa.w = packbf(fmaxf(accA6 * ra + biA1.z, 0.f), fmaxf(accA7 * ra + biA1.w, 0.f));
    *(uint4*)(op + 4 * m) = pa;
    uint2 pb;
    pb.x = packbf(fmaxf(accB0 * rb + biB.x, 0.f), fmaxf(accB1 * rb + biB.y, 0.f));
    pb.y = packbf(fmaxf(accB2 * rb + biB.z, 0.f), fmaxf(accB3 * rb + biB.w, 0.f));
    *(uint2*)(op + 64 + 2 * m) = pb;
  }
}

// layer2: 96 ch (48 dwords), 1 head. Wave per node; group g=lane>>4 handles staged
// edge j+g (4 edges/iter); lane m=lane&15 owns dwords {2m,2m+1} (uint2) + {32+m}.
// den: each group sums its own edges' weights; xor-16/32 reduce counts each group once.
__global__ __launch_bounds__(256) void k_agg2(const unsigned short* __restrict__ h,
                                              const float* __restrict__ asrc,
                                              const float* __restrict__ adst,
                                              const int* __restrict__ row_off,
                                              const int* __restrict__ col,
                                              const float* __restrict__ b2,
                                              float* __restrict__ out, int N) {
  __shared__ int2 eL[4][64];
  int wid = threadIdx.x >> 6;
  int node = blockIdx.x * 4 + wid;
  if (node >= N) return;
  int lane = threadIdx.x & 63;
  int g = lane >> 4;
  int m = lane & 15;
  int beg = __builtin_amdgcn_readfirstlane(row_off[node]);
  int end = __builtin_amdgcn_readfirstlane(row_off[node + 1]);
  float ad = adst[node];
  float a0 = 0, a1 = 0, a2 = 0, a3 = 0, a4 = 0, a5 = 0;
  float den = 0.f;
  const unsigned* h32 = (const unsigned*)h;
  for (int base = beg; base < end; base += 64) {
    int cnt = end - base;
    if (cnt > 64) cnt = 64;
    int s = 0;
    float w = 0.f;
    if (lane < cnt) {
      s = col[base + lane];
      w = __expf(LRELU(asrc[s] + ad));
    }
    eL[wid][lane] = make_int2(s, __builtin_bit_cast(int, w));
    wave_lds_fence();
    int jmax = (cnt + 3) & ~3;
#pragma unroll 4
    for (int j = 0; j < jmax; j += 4) {
      int2 e = eL[wid][j + g];
      int sj = e.x;
      float wj = __builtin_bit_cast(float, e.y);
      den += wj;
      const unsigned* hp = h32 + (size_t)sj * 48;
      uint2 v0 = *(const uint2*)(hp + 2 * m);
      unsigned v1 = hp[32 + m];
      a0 += wj * bfLO(v0.x);
      a1 += wj * bfHI(v0.x);
      a2 += wj * bfLO(v0.y);
      a3 += wj * bfHI(v0.y);
      a4 += wj * bfLO(v1);
      a5 += wj * bfHI(v1);
    }
    __builtin_amdgcn_wave_barrier();
  }
#define RED2(x) x += __shfl_xor(x, 16); x += __shfl_xor(x, 32)
  RED2(den);
  RED2(a0); RED2(a1); RED2(a2); RED2(a3); RED2(a4); RED2(a5);
#undef RED2
  if (g == 0) {
    float r = 1.f / den;
    float* op = out + (size_t)node * 96;
    float4 bi0 = *(const float4*)&b2[4 * m];
    float2 bi1 = *(const float2*)&b2[64 + 2 * m];
    float4 o0;
    o0.x = fmaxf(a0 * r + bi0.x, 0.f);
    o0.y = fmaxf(a1 * r + bi0.y, 0.f);
    o0.z = fmaxf(a2 * r + bi0.z, 0.f);
    o0.w = fmaxf(a3 * r + bi0.w, 0.f);
    *(float4*)(op + 4 * m) = o0;
    float2 o1;
    o1.x = fmaxf(a4 * r + bi1.x, 0.f);
    o1.y = fmaxf(a5 * r + bi1.y, 0.f);
    *(float2*)(op + 64 + 2 * m) = o1;
  }
}

// ---------------- pool (mean per graph) + MLP ----------------

__global__ __launch_bounds__(384) void k_pool_mlp(const float* __restrict__ o2,
                                                  const int* __restrict__ batch, int N,
                                                  const float* __restrict__ fc1w,
                                                  const float* __restrict__ fc1b,
                                                  const float* __restrict__ fc2w,
                                                  const float* __restrict__ fc2b,
                                                  float* __restrict__ out) {
  int g = blockIdx.x;
  int t = threadIdx.x;
  int lo = 0, hi = N;
  while (lo < hi) { int mid = (lo + hi) >> 1; if (batch[mid] < g) lo = mid + 1; else hi = mid; }
  int lo2 = lo;
  int l = lo, hh = N;
  while (l < hh) { int mid = (l + hh) >> 1; if (batch[mid] < g + 1) l = mid + 1; else hh = mid; }
  int hi2 = l;

  __shared__ float part[4][96];
  __shared__ float pooled[96];
  __shared__ float z[192];
  int grp = t / 96, c = t % 96;
  float s = 0.f;
  for (int n = lo2 + grp; n < hi2; n += 4) s += o2[(size_t)n * 96 + c];
  part[grp][c] = s;
  __syncthreads();
  if (t < 96) {
    float tot = part[0][t] + part[1][t] + part[2][t] + part[3][t];
    pooled[t] = tot / fmaxf((float)(hi2 - lo2), 1.0f);
  }
  __syncthreads();
  if (t < 192) {
    float a = fc1b[t];
#pragma unroll 4
    for (int cc = 0; cc < 96; ++cc) a += pooled[cc] * fc1w[cc * 192 + t];
    z[t] = fmaxf(a, 0.f);
  }
  __syncthreads();
  if (t < 96) {
    float a = fc2b[t];
#pragma unroll 4
    for (int j = 0; j < 192; ++j) a += z[j] * fc2w[j * 96 + t];
    out[g * 96 + t] = a;
  }
}

// ---------------- launch ----------------

extern "C" void kernel_launch(void* const* d_in, const int* in_sizes, int n_in,
                              void* d_out, int out_size, void* d_ws, size_t ws_size,
                              hipStream_t stream) {
  const float* x = (const float*)d_in[0];
  const int* ei = (const int*)d_in[1];
  const int* batch = (const int*)d_in[2];
  const float* W1 = (const float*)d_in[3];
  const float* a_src1 = (const float*)d_in[4];
  const float* a_dst1 = (const float*)d_in[5];
  const float* b1 = (const float*)d_in[6];
  const float* W2 = (const float*)d_in[7];
  const float* a_src2 = (const float*)d_in[8];
  const float* a_dst2 = (const float*)d_in[9];
  const float* b2 = (const float*)d_in[10];
  const float* fc1w = (const float*)d_in[11];
  const float* fc1b = (const float*)d_in[12];
  const float* fc2w = (const float*)d_in[13];
  const float* fc2b = (const float*)d_in[14];
  float* out = (float*)d_out;

  const int N = in_sizes[2];          // 100000 nodes
  const int E = in_sizes[1] / 2;      // 1.6M edges
  const int G = out_size / 96;        // 128 graphs
  const int NBK = (N + 255) >> 8;     // coarse buckets (391)
  const int chunk = (E + NSB - 1) / NSB;

  size_t off = 0;
  auto alloc = [&](size_t bytes) {
    void* p = (char*)d_ws + off;
    off += (bytes + 255) & ~(size_t)255;
    return p;
  };
  unsigned short* h_bf = (unsigned short*)alloc((size_t)N * 192 * 2);   // h1, later h2
  unsigned short* o1_bf = (unsigned short*)alloc((size_t)N * 192 * 2);  // layer1 out
  float* o2_f = (float*)alloc((size_t)N * 96 * 4);                      // layer2 out
  float* asrc1 = (float*)alloc((size_t)N * 4 * 4);
  float* adst1 = (float*)alloc((size_t)N * 4 * 4);
  float* asrc2 = (float*)alloc((size_t)N * 4);
  float* adst2 = (float*)alloc((size_t)N * 4);
  unsigned short* W1h = (unsigned short*)alloc((size_t)192 * 128 * 2);
  unsigned short* W1l = (unsigned short*)alloc((size_t)192 * 128 * 2);
  unsigned short* W2h = (unsigned short*)alloc((size_t)96 * 192 * 2);
  unsigned short* W2l = (unsigned short*)alloc((size_t)96 * 192 * 2);
  int* row_off = (int*)alloc((size_t)(N + 1) * 4);
  int* col = (int*)alloc((size_t)(E + N) * 4);
  int* pairs = (int*)alloc((size_t)E * 4);
  int* cntmat = (int*)alloc((size_t)NBK * NSB * 4);
  int* bucket_tot = (int*)alloc((size_t)NBK * 4);
  int* bucket_off = (int*)alloc((size_t)(NBK + 1) * 4);
  (void)ws_size;

  const int* src = ei;
  const int* dst = ei + E;

  // --- weight conversion (one launch, both layers) ---
  k_convW<<<(128 * 192 + 192 * 96 + 255) / 256, 256, 0, stream>>>(W1, W2, W1h, W1l, W2h, W2l);

  // --- binned CSR build (atomic-free global ordering) ---
  k_hist2<<<NSB, 256, 0, stream>>>(dst, E, chunk, NBK, cntmat);
  k_rowscan<<<NBK, 256, 0, stream>>>(cntmat, bucket_tot);
  k_bscan<<<1, 512, 0, stream>>>(bucket_tot, NBK, bucket_off, row_off, N, E);
  k_scatter2<<<NSB, 256, 0, stream>>>(src, dst, E, chunk, NBK, bucket_off, cntmat, pairs);
  k_bbuild<<<NBK, 256, 0, stream>>>(pairs, bucket_off, N, row_off, col);

  int gblk = (N + 127) / 128;
  int nblk4 = (N + 3) / 4;

  // --- layer 1 ---
  k_gemm_mfma<128, 192, false><<<gblk, 256, 0, stream>>>(x, W1h, W1l, h_bf, N);
  k_coef1<<<nblk4, 256, 0, stream>>>(h_bf, a_src1, a_dst1, asrc1, adst1, N);
  k_agg1<<<nblk4, 256, 0, stream>>>(h_bf, asrc1, adst1, row_off, col, b1, o1_bf, N);

  // --- layer 2 ---
  k_gemm_mfma<192, 96, true><<<gblk, 256, 0, stream>>>(o1_bf, W2h, W2l, h_bf, N);
  k_coef2<<<nblk4, 256, 0, stream>>>(h_bf, a_src2, a_dst2, asrc2, adst2, N);
  k_agg2<<<nblk4, 256, 0, stream>>>(h_bf, asrc2, adst2, row_off, col, b2, o2_f, N);

  // --- pool + MLP ---
  k_pool_mlp<<<G, 384, 0, stream>>>(o2_f, batch, N, fc1w, fc1b, fc2w, fc2b, out);
}

// Round 10
// 492.313 us; speedup vs baseline: 1.0530x; 1.0530x over previous
//
#include <hip/hip_runtime.h>

// GAT 2-layer + mean-pool + MLP. bf16 internal features, MFMA GEMMs (hi/lo split W),
// atomic-free binned CSR build.
// Round 10: (a) agg1 reverted to unroll 2 (R9's unroll 4 -> VGPR 52 -> occupancy 38%
// -> slower; latency-bound kernels need waves more than in-wave ILP). (b) pool_mlp
// split: k_pool (G x 8 blocks, deterministic partials) + k_mlp (G blocks) -- the old
// single-kernel version chained ~195 dependent loads on 128 blocks (~35 us).

#define LRELU(x) fmaxf((x), 0.2f * (x))

using bf16x8 = __attribute__((ext_vector_type(8))) short;
using f32x16 = __attribute__((ext_vector_type(16))) float;

#define NSB 256  // scatter blocks (fixed; cntmat is [NBK][NSB])

__device__ inline unsigned short f2bf(float f) {
  unsigned u = __builtin_bit_cast(unsigned, f);
  return (unsigned short)((u + 0x7fffu + ((u >> 16) & 1u)) >> 16);  // RNE
}
__device__ inline float bf2f(unsigned short h) {
  return __builtin_bit_cast(float, (unsigned)h << 16);
}
__device__ inline float bfLO(unsigned v) { return __builtin_bit_cast(float, v << 16); }
__device__ inline float bfHI(unsigned v) { return __builtin_bit_cast(float, v & 0xffff0000u); }
__device__ inline unsigned packbf(float a, float b) {
  return (unsigned)f2bf(a) | ((unsigned)f2bf(b) << 16);
}

// wave-synchronous LDS publish: all lanes' ds_writes drained before any ds_read.
__device__ inline void wave_lds_fence() {
  __builtin_amdgcn_wave_barrier();
  __builtin_amdgcn_s_waitcnt(0xc07f);  // lgkmcnt(0)
  __builtin_amdgcn_wave_barrier();
}

// ---------------- binned CSR build ----------------
// bucket b = dst >> 8 covers dsts [b*256, b*256+256). NBK = ceil(N/256) <= 512.

__global__ __launch_bounds__(256) void k_hist2(const int* __restrict__ dst, int E, int chunk,
                                               int NBK, int* __restrict__ cntmat) {
  __shared__ int lh[512];
  int b = blockIdx.x, t = threadIdx.x;
  for (int i = t; i < NBK; i += 256) lh[i] = 0;
  __syncthreads();
  int beg = b * chunk, end = min(E, beg + chunk);
  for (int e = beg + t; e < end; e += 256) atomicAdd(&lh[dst[e] >> 8], 1);
  __syncthreads();
  for (int i = t; i < NBK; i += 256) cntmat[i * NSB + b] = lh[i];
}

__global__ __launch_bounds__(256) void k_rowscan(int* __restrict__ cntmat,
                                                 int* __restrict__ bucket_tot) {
  int k = blockIdx.x, t = threadIdx.x;
  __shared__ int sc[256];
  int v = cntmat[k * NSB + t];
  sc[t] = v;
  __syncthreads();
  for (int off = 1; off < 256; off <<= 1) {
    int add = (t >= off) ? sc[t - off] : 0;
    __syncthreads();
    sc[t] += add;
    __syncthreads();
  }
  cntmat[k * NSB + t] = sc[t] - v;
  if (t == 255) bucket_tot[k] = sc[t];
}

__global__ __launch_bounds__(512) void k_bscan(const int* __restrict__ bucket_tot, int NBK,
                                               int* __restrict__ bucket_off,
                                               int* __restrict__ row_off, int N, int E) {
  __shared__ int sc[512];
  int t = threadIdx.x;
  int v = (t < NBK) ? bucket_tot[t] : 0;
  sc[t] = v;
  __syncthreads();
  for (int off = 1; off < 512; off <<= 1) {
    int add = (t >= off) ? sc[t - off] : 0;
    __syncthreads();
    sc[t] += add;
    __syncthreads();
  }
  int excl = sc[t] - v;
  if (t < NBK) {
    bucket_off[t] = excl;
    if (t == NBK - 1) bucket_off[NBK] = excl + v;
  }
  if (t == 0) row_off[N] = E + N;
}

__global__ __launch_bounds__(256) void k_scatter2(const int* __restrict__ src,
                                                  const int* __restrict__ dst, int E, int chunk,
                                                  int NBK, const int* __restrict__ bucket_off,
                                                  const int* __restrict__ cntmat,
                                                  int* __restrict__ pairs) {
  __shared__ int base[512];
  __shared__ int cur[512];
  int b = blockIdx.x, t = threadIdx.x;
  for (int i = t; i < NBK; i += 256) {
    base[i] = bucket_off[i] + cntmat[i * NSB + b];
    cur[i] = 0;
  }
  __syncthreads();
  int beg = b * chunk, end = min(E, beg + chunk);
  for (int e = beg + t; e < end; e += 256) {
    int s = src[e], d = dst[e];
    int k = d >> 8;
    int loc = atomicAdd(&cur[k], 1);  // LDS atomic: block-private
    pairs[base[k] + loc] = (s << 8) | (d & 255);
  }
}

#define BBUILD_CAP 8448
__global__ __launch_bounds__(256) void k_bbuild(const int* __restrict__ pairs,
                                                const int* __restrict__ bucket_off,
                                                int N, int* __restrict__ row_off,
                                                int* __restrict__ col) {
  int b = blockIdx.x;
  int t = threadIdx.x;
  int base_d = b * 256;
  int nd = N - base_d;
  if (nd > 256) nd = 256;
  int pbeg = bucket_off[b], pend = bucket_off[b + 1];
  int cntb = pend - pbeg;
  int colbase = pbeg + base_d;

  __shared__ int hist[256];
  __shared__ int scn[256];
  __shared__ int cur[256];
  __shared__ int colL[BBUILD_CAP];
  hist[t] = 0;
  __syncthreads();
  for (int p = pbeg + t; p < pend; p += 256) atomicAdd(&hist[pairs[p] & 255], 1);
  __syncthreads();
  int v = (t < nd) ? hist[t] + 1 : 0;
  scn[t] = v;
  __syncthreads();
  for (int off = 1; off < 256; off <<= 1) {
    int add = (t >= off) ? scn[t - off] : 0;
    __syncthreads();
    scn[t] += add;
    __syncthreads();
  }
  int excl = scn[t] - v;
  if (t < nd) row_off[base_d + t] = colbase + excl;
  int total = cntb + nd;
  if (total <= BBUILD_CAP) {
    cur[t] = excl;
    if (t < nd) colL[excl + hist[t]] = base_d + t;
    __syncthreads();
    for (int p = pbeg + t; p < pend; p += 256) {
      int w = pairs[p];
      int lp = atomicAdd(&cur[w & 255], 1);
      colL[lp] = w >> 8;
    }
    __syncthreads();
    for (int i = t; i < total; i += 256) col[colbase + i] = colL[i];
  } else {
    cur[t] = excl;
    if (t < nd) col[colbase + excl + hist[t]] = base_d + t;
    __syncthreads();
    for (int p = pbeg + t; p < pend; p += 256) {
      int w = pairs[p];
      int lp = atomicAdd(&cur[w & 255], 1);
      col[colbase + lp] = w >> 8;
    }
  }
}

// ---------------- weight conversion (both layers, one launch) ----------------

__global__ __launch_bounds__(256) void k_convW(const float* __restrict__ W1,
                                               const float* __restrict__ W2,
                                               unsigned short* __restrict__ T1h,
                                               unsigned short* __restrict__ T1l,
                                               unsigned short* __restrict__ T2h,
                                               unsigned short* __restrict__ T2l) {
  const int E1 = 128 * 192;  // W1: K=128, N=192
  const int E2 = 192 * 96;   // W2: K=192, N=96
  int idx = blockIdx.x * 256 + threadIdx.x;
  if (idx < E1) {
    int k = idx / 192, n = idx - k * 192;
    float w = W1[idx];
    unsigned short hi = f2bf(w);
    unsigned short lo = f2bf(w - bf2f(hi));
    T1h[n * 128 + k] = hi;
    T1l[n * 128 + k] = lo;
  } else if (idx < E1 + E2) {
    int i2 = idx - E1;
    int k = i2 / 96, n = i2 - k * 96;
    float w = W2[i2];
    unsigned short hi = f2bf(w);
    unsigned short lo = f2bf(w - bf2f(hi));
    T2h[n * 192 + k] = hi;
    T2l[n * 192 + k] = lo;
  }
}

// ---------------- MFMA GEMM: C[M,N](bf16) = A[M,K] @ (Bh+Bl) ----------------

template <int K, int N, bool A_BF16>
__global__ __launch_bounds__(256) void k_gemm_mfma(const void* __restrict__ Ap,
                                                   const unsigned short* __restrict__ Bh,
                                                   const unsigned short* __restrict__ Bl,
                                                   unsigned short* __restrict__ C, int M) {
  constexpr int NT = N / 32;
  __shared__ unsigned short As[128 * 40];
  __shared__ unsigned short Bhs[N * 40];
  __shared__ unsigned short Bls[N * 40];
  int tid = threadIdx.x;
  int wave = tid >> 6, lane = tid & 63;
  int bm = blockIdx.x * 128;

  f32x16 acc[NT];
#pragma unroll
  for (int t = 0; t < NT; ++t)
#pragma unroll
    for (int i = 0; i < 16; ++i) acc[t][i] = 0.f;

  for (int k0 = 0; k0 < K; k0 += 32) {
#pragma unroll
    for (int i = 0; i < 2; ++i) {
      int unit = tid + i * 256;
      int r = unit >> 2, u = unit & 3;
      int gr = bm + r;
      uint4 o = make_uint4(0, 0, 0, 0);
      if (gr < M) {
        if (A_BF16) {
          o = *(const uint4*)((const unsigned short*)Ap + (size_t)gr * K + k0 + u * 8);
        } else {
          const float* af = (const float*)Ap + (size_t)gr * K + k0 + u * 8;
          float4 v0 = *(const float4*)af;
          float4 v1 = *(const float4*)(af + 4);
          o.x = (unsigned)f2bf(v0.x) | ((unsigned)f2bf(v0.y) << 16);
          o.y = (unsigned)f2bf(v0.z) | ((unsigned)f2bf(v0.w) << 16);
          o.z = (unsigned)f2bf(v1.x) | ((unsigned)f2bf(v1.y) << 16);
          o.w = (unsigned)f2bf(v1.z) | ((unsigned)f2bf(v1.w) << 16);
        }
      }
      *(uint4*)&As[r * 40 + u * 8] = o;
    }
    for (int unit = tid; unit < N * 4; unit += 256) {
      int n = unit >> 2, u = unit & 3;
      *(uint4*)&Bhs[n * 40 + u * 8] = *(const uint4*)&Bh[n * K + k0 + u * 8];
      *(uint4*)&Bls[n * 40 + u * 8] = *(const uint4*)&Bl[n * K + k0 + u * 8];
    }
    __syncthreads();

    int arow = wave * 32 + (lane & 31);
    int fo = (lane >> 5) * 8;
#pragma unroll
    for (int s = 0; s < 2; ++s) {
      bf16x8 af = *(const bf16x8*)&As[arow * 40 + s * 16 + fo];
#pragma unroll
      for (int t = 0; t < NT; ++t) {
        bf16x8 bh = *(const bf16x8*)&Bhs[(t * 32 + (lane & 31)) * 40 + s * 16 + fo];
        bf16x8 bl = *(const bf16x8*)&Bls[(t * 32 + (lane & 31)) * 40 + s * 16 + fo];
        acc[t] = __builtin_amdgcn_mfma_f32_32x32x16_bf16(af, bh, acc[t], 0, 0, 0);
        acc[t] = __builtin_amdgcn_mfma_f32_32x32x16_bf16(af, bl, acc[t], 0, 0, 0);
      }
    }
    __syncthreads();
  }

#pragma unroll
  for (int t = 0; t < NT; ++t) {
    int col = t * 32 + (lane & 31);
#pragma unroll
    for (int r = 0; r < 16; ++r) {
      int row = wave * 32 + (r & 3) + 8 * (r >> 2) + 4 * (lane >> 5);
      int gr = bm + row;
      if (gr < M) C[(size_t)gr * N + col] = f2bf(acc[t][r]);
    }
  }
}

// ---------------- attention coefficients (h in bf16, dword loads) ----------------

__global__ __launch_bounds__(256) void k_coef1(const unsigned short* __restrict__ h,
                                               const float* __restrict__ a_src,
                                               const float* __restrict__ a_dst,
                                               float* __restrict__ asrc,
                                               float* __restrict__ adst, int N) {
  int node = blockIdx.x * 4 + (threadIdx.x >> 6);
  if (node >= N) return;
  int m = threadIdx.x & 63;
  const unsigned* hp = (const unsigned*)h + (size_t)node * 96;
  unsigned va = hp[m];
  float x0 = bfLO(va), x1 = bfHI(va);
  float2 as = *(const float2*)&a_src[2 * m];
  float2 ad = *(const float2*)&a_dst[2 * m];
  float pas = x0 * as.x + x1 * as.y;
  float pad = x0 * ad.x + x1 * ad.y;
  int ha = m / 24;
  float pbs = 0.f, pbd = 0.f;
  int hb = (m < 8) ? 2 : 3;
  if (m < 32) {
    unsigned vb = hp[64 + m];
    float y0 = bfLO(vb), y1 = bfHI(vb);
    float2 bs = *(const float2*)&a_src[128 + 2 * m];
    float2 bd = *(const float2*)&a_dst[128 + 2 * m];
    pbs = y0 * bs.x + y1 * bs.y;
    pbd = y0 * bd.x + y1 * bd.y;
  }
  float4 cs, cd;
  cs.x = (ha == 0) ? pas : 0.f;
  cs.y = (ha == 1) ? pas : 0.f;
  cs.z = ((ha == 2) ? pas : 0.f) + ((hb == 2) ? pbs : 0.f);
  cs.w = (hb == 3) ? pbs : 0.f;
  cd.x = (ha == 0) ? pad : 0.f;
  cd.y = (ha == 1) ? pad : 0.f;
  cd.z = ((ha == 2) ? pad : 0.f) + ((hb == 2) ? pbd : 0.f);
  cd.w = (hb == 3) ? pbd : 0.f;
#pragma unroll
  for (int off = 1; off < 64; off <<= 1) {
    cs.x += __shfl_xor(cs.x, off);
    cs.y += __shfl_xor(cs.y, off);
    cs.z += __shfl_xor(cs.z, off);
    cs.w += __shfl_xor(cs.w, off);
    cd.x += __shfl_xor(cd.x, off);
    cd.y += __shfl_xor(cd.y, off);
    cd.z += __shfl_xor(cd.z, off);
    cd.w += __shfl_xor(cd.w, off);
  }
  if (m == 0) {
    *(float4*)&asrc[node * 4] = cs;
    *(float4*)&adst[node * 4] = cd;
  }
}

__global__ __launch_bounds__(256) void k_coef2(const unsigned short* __restrict__ h,
                                               const float* __restrict__ a_src,
                                               const float* __restrict__ a_dst,
                                               float* __restrict__ asrc,
                                               float* __restrict__ adst, int N) {
  int node = blockIdx.x * 4 + (threadIdx.x >> 6);
  if (node >= N) return;
  int m = threadIdx.x & 63;
  float ps = 0.f, pd = 0.f;
  if (m < 48) {
    unsigned v = ((const unsigned*)h)[(size_t)node * 48 + m];
    float x0 = bfLO(v), x1 = bfHI(v);
    float2 as = *(const float2*)&a_src[2 * m];
    float2 ad = *(const float2*)&a_dst[2 * m];
    ps = x0 * as.x + x1 * as.y;
    pd = x0 * ad.x + x1 * ad.y;
  }
#pragma unroll
  for (int off = 1; off < 64; off <<= 1) {
    ps += __shfl_xor(ps, off);
    pd += __shfl_xor(pd, off);
  }
  if (m == 0) {
    asrc[node] = ps;
    adst[node] = pd;
  }
}

// ---------------- aggregation: quarter-wave gather, LDS weight broadcast ----------------

// layer1: 192 ch (96 dwords), 4 heads. Wave per node; quarter q handles staged edge
// j+q; lane m=lane&15 owns dwords {4m..4m+3} (uint4, head m/6) and {64+2m,65+2m}
// (uint2, head m<4?2:3). 4 edges per iteration. Padded staged entries have w=0.
// unroll 2 (NOT 4: R9 showed unroll 4 -> VGPR 52 -> occupancy 38% -> slower).
__global__ __launch_bounds__(256) void k_agg1(const unsigned short* __restrict__ h,
                                              const float* __restrict__ asrc,
                                              const float* __restrict__ adst,
                                              const int* __restrict__ row_off,
                                              const int* __restrict__ col,
                                              const float* __restrict__ b1,
                                              unsigned short* __restrict__ out, int N) {
  __shared__ int sL[4][64];
  __shared__ float wL[4][64][4];
  int wid = threadIdx.x >> 6;
  int node = blockIdx.x * 4 + wid;
  if (node >= N) return;
  int lane = threadIdx.x & 63;
  int q = lane >> 4;
  int m = lane & 15;
  int hA = m / 6;            // head of dwords 4m..4m+3 (ch 8m..8m+7)
  int hB = (m < 4) ? 2 : 3;  // head of dwords 64+2m (ch 128+4m..131+4m)
  int beg = __builtin_amdgcn_readfirstlane(row_off[node]);
  int end = __builtin_amdgcn_readfirstlane(row_off[node + 1]);
  float4 ad = *(const float4*)&adst[node * 4];
  float accA0 = 0, accA1 = 0, accA2 = 0, accA3 = 0;
  float accA4 = 0, accA5 = 0, accA6 = 0, accA7 = 0;
  float accB0 = 0, accB1 = 0, accB2 = 0, accB3 = 0;
  float da = 0.f, db = 0.f;
  const unsigned* h32 = (const unsigned*)h;
  for (int base = beg; base < end; base += 64) {
    int cnt = end - base;
    if (cnt > 64) cnt = 64;
    int s = 0;
    float w0 = 0.f, w1 = 0.f, w2 = 0.f, w3 = 0.f;
    if (lane < cnt) {
      s = col[base + lane];
      float4 as = *(const float4*)&asrc[s * 4];
      w0 = __expf(LRELU(as.x + ad.x));
      w1 = __expf(LRELU(as.y + ad.y));
      w2 = __expf(LRELU(as.z + ad.z));
      w3 = __expf(LRELU(as.w + ad.w));
    }
    sL[wid][lane] = s;
    *(float4*)&wL[wid][lane][0] = make_float4(w0, w1, w2, w3);
    wave_lds_fence();
    int jmax = (cnt + 3) & ~3;
#pragma unroll 2
    for (int j = 0; j < jmax; j += 4) {
      int je = j + q;
      int sj = sL[wid][je];
      float wa = wL[wid][je][hA];
      float wb = wL[wid][je][hB];
      const unsigned* hp = h32 + (size_t)sj * 96;
      uint4 va = *(const uint4*)(hp + 4 * m);
      uint2 vb = *(const uint2*)(hp + 64 + 2 * m);
      da += wa;
      db += wb;
      accA0 += wa * bfLO(va.x);
      accA1 += wa * bfHI(va.x);
      accA2 += wa * bfLO(va.y);
      accA3 += wa * bfHI(va.y);
      accA4 += wa * bfLO(va.z);
      accA5 += wa * bfHI(va.z);
      accA6 += wa * bfLO(va.w);
      accA7 += wa * bfHI(va.w);
      accB0 += wb * bfLO(vb.x);
      accB1 += wb * bfHI(vb.x);
      accB2 += wb * bfLO(vb.y);
      accB3 += wb * bfHI(vb.y);
    }
    __builtin_amdgcn_wave_barrier();  // reads done before next chunk overwrites
  }
  // combine the four quarters
#define RED2(x) x += __shfl_xor(x, 16); x += __shfl_xor(x, 32)
  RED2(da); RED2(db);
  RED2(accA0); RED2(accA1); RED2(accA2); RED2(accA3);
  RED2(accA4); RED2(accA5); RED2(accA6); RED2(accA7);
  RED2(accB0); RED2(accB1); RED2(accB2); RED2(accB3);
#undef RED2
  if (q == 0) {
    float ra = 1.f / da, rb = 1.f / db;
    float4 biA0 = *(const float4*)&b1[8 * m];
    float4 biA1 = *(const float4*)&b1[8 * m + 4];
    float4 biB = *(const float4*)&b1[128 + 4 * m];
    unsigned* op = (unsigned*)(out + (size_t)node * 192);
    uint4 pa;
    pa.x = packbf(fmaxf(accA0 * ra + biA0.x, 0.f), fmaxf(accA1 * ra + biA0.y, 0.f));
    pa.y = packbf(fmaxf(accA2 * ra + biA0.z, 0.f), fmaxf(accA3 * ra + biA0.w, 0.f));
    pa.z = packbf(fmaxf(accA4 * ra + biA1.x, 0.f), fmaxf(accA5 * ra + biA1.y, 0.f));
    pa.w = packbf(fmaxf(accA6 * ra + biA1.z, 0.f), fmaxf(accA7 * ra + biA1.w, 0.f));
    *(uint4*)(op + 4 * m) = pa;
    uint2 pb;
    pb.x = packbf(fmaxf(accB0 * rb + biB.x, 0.f), fmaxf(accB1 * rb + biB.y, 0.f));
    pb.y = packbf(fmaxf(accB2 * rb + biB.z, 0.f), fmaxf(accB3 * rb + biB.w, 0.f));
    *(uint2*)(op + 64 + 2 * m) = pb;
  }
}

// layer2: 96 ch (48 dwords), 1 head. Wave per node; group g=lane>>4 handles staged
// edge j+g (4 edges/iter); lane m=lane&15 owns dwords {2m,2m+1} (uint2) + {32+m}.
__global__ __launch_bounds__(256) void k_agg2(const unsigned short* __restrict__ h,
                                              const float* __restrict__ asrc,
                                              const float* __restrict__ adst,
                                              const int* __restrict__ row_off,
                                              const int* __restrict__ col,
                                              const float* __restrict__ b2,
                                              float* __restrict__ out, int N) {
  __shared__ int2 eL[4][64];
  int wid = threadIdx.x >> 6;
  int node = blockIdx.x * 4 + wid;
  if (node >= N) return;
  int lane = threadIdx.x & 63;
  int g = lane >> 4;
  int m = lane & 15;
  int beg = __builtin_amdgcn_readfirstlane(row_off[node]);
  int end = __builtin_amdgcn_readfirstlane(row_off[node + 1]);
  float ad = adst[node];
  float a0 = 0, a1 = 0, a2 = 0, a3 = 0, a4 = 0, a5 = 0;
  float den = 0.f;
  const unsigned* h32 = (const unsigned*)h;
  for (int base = beg; base < end; base += 64) {
    int cnt = end - base;
    if (cnt > 64) cnt = 64;
    int s = 0;
    float w = 0.f;
    if (lane < cnt) {
      s = col[base + lane];
      w = __expf(LRELU(asrc[s] + ad));
    }
    eL[wid][lane] = make_int2(s, __builtin_bit_cast(int, w));
    wave_lds_fence();
    int jmax = (cnt + 3) & ~3;
#pragma unroll 4
    for (int j = 0; j < jmax; j += 4) {
      int2 e = eL[wid][j + g];
      int sj = e.x;
      float wj = __builtin_bit_cast(float, e.y);
      den += wj;
      const unsigned* hp = h32 + (size_t)sj * 48;
      uint2 v0 = *(const uint2*)(hp + 2 * m);
      unsigned v1 = hp[32 + m];
      a0 += wj * bfLO(v0.x);
      a1 += wj * bfHI(v0.x);
      a2 += wj * bfLO(v0.y);
      a3 += wj * bfHI(v0.y);
      a4 += wj * bfLO(v1);
      a5 += wj * bfHI(v1);
    }
    __builtin_amdgcn_wave_barrier();
  }
#define RED2(x) x += __shfl_xor(x, 16); x += __shfl_xor(x, 32)
  RED2(den);
  RED2(a0); RED2(a1); RED2(a2); RED2(a3); RED2(a4); RED2(a5);
#undef RED2
  if (g == 0) {
    float r = 1.f / den;
    float* op = out + (size_t)node * 96;
    float4 bi0 = *(const float4*)&b2[4 * m];
    float2 bi1 = *(const float2*)&b2[64 + 2 * m];
    float4 o0;
    o0.x = fmaxf(a0 * r + bi0.x, 0.f);
    o0.y = fmaxf(a1 * r + bi0.y, 0.f);
    o0.z = fmaxf(a2 * r + bi0.z, 0.f);
    o0.w = fmaxf(a3 * r + bi0.w, 0.f);
    *(float4*)(op + 4 * m) = o0;
    float2 o1;
    o1.x = fmaxf(a4 * r + bi1.x, 0.f);
    o1.y = fmaxf(a5 * r + bi1.y, 0.f);
    *(float2*)(op + 64 + 2 * m) = o1;
  }
}

// ---------------- pool (mean per graph): G x 8 blocks of partials, then MLP ----------------

__global__ __launch_bounds__(384) void k_pool(const float* __restrict__ o2,
                                              const int* __restrict__ batch, int N,
                                              float* __restrict__ part) {
  int g = blockIdx.x >> 3;
  int i = blockIdx.x & 7;
  int t = threadIdx.x;
  int grp = t / 96, c = t % 96;  // 4 groups of 96
  int lo = 0, hi = N;
  while (lo < hi) { int mid = (lo + hi) >> 1; if (batch[mid] < g) lo = mid + 1; else hi = mid; }
  int lo2 = lo;
  int l = lo, hh = N;
  while (l < hh) { int mid = (l + hh) >> 1; if (batch[mid] < g + 1) l = mid + 1; else hh = mid; }
  int hi2 = l;
  float s = 0.f;
  for (int n = lo2 + i + 8 * grp; n < hi2; n += 32) s += o2[(size_t)n * 96 + c];
  __shared__ float red[4][96];
  red[grp][c] = s;
  __syncthreads();
  if (t < 96) part[(size_t)blockIdx.x * 96 + t] = red[0][t] + red[1][t] + red[2][t] + red[3][t];
}

__global__ __launch_bounds__(192) void k_mlp(const float* __restrict__ part,
                                             const int* __restrict__ batch, int N,
                                             const float* __restrict__ fc1w,
                                             const float* __restrict__ fc1b,
                                             const float* __restrict__ fc2w,
                                             const float* __restrict__ fc2b,
                                             float* __restrict__ out) {
  int g = blockIdx.x;
  int t = threadIdx.x;
  int lo = 0, hi = N;
  while (lo < hi) { int mid = (lo + hi) >> 1; if (batch[mid] < g) lo = mid + 1; else hi = mid; }
  int lo2 = lo;
  int l = lo, hh = N;
  while (l < hh) { int mid = (l + hh) >> 1; if (batch[mid] < g + 1) l = mid + 1; else hh = mid; }
  int hi2 = l;

  __shared__ float pooled[96];
  __shared__ float z[192];
  if (t < 96) {
    float s = 0.f;
#pragma unroll
    for (int i = 0; i < 8; ++i) s += part[(size_t)(g * 8 + i) * 96 + t];
    pooled[t] = s / fmaxf((float)(hi2 - lo2), 1.0f);
  }
  __syncthreads();
  {
    float a = fc1b[t];
#pragma unroll 4
    for (int cc = 0; cc < 96; ++cc) a += pooled[cc] * fc1w[cc * 192 + t];
    z[t] = fmaxf(a, 0.f);
  }
  __syncthreads();
  if (t < 96) {
    float a = fc2b[t];
#pragma unroll 4
    for (int j = 0; j < 192; ++j) a += z[j] * fc2w[j * 96 + t];
    out[g * 96 + t] = a;
  }
}

// ---------------- launch ----------------

extern "C" void kernel_launch(void* const* d_in, const int* in_sizes, int n_in,
                              void* d_out, int out_size, void* d_ws, size_t ws_size,
                              hipStream_t stream) {
  const float* x = (const float*)d_in[0];
  const int* ei = (const int*)d_in[1];
  const int* batch = (const int*)d_in[2];
  const float* W1 = (const float*)d_in[3];
  const float* a_src1 = (const float*)d_in[4];
  const float* a_dst1 = (const float*)d_in[5];
  const float* b1 = (const float*)d_in[6];
  const float* W2 = (const float*)d_in[7];
  const float* a_src2 = (const float*)d_in[8];
  const float* a_dst2 = (const float*)d_in[9];
  const float* b2 = (const float*)d_in[10];
  const float* fc1w = (const float*)d_in[11];
  const float* fc1b = (const float*)d_in[12];
  const float* fc2w = (const float*)d_in[13];
  const float* fc2b = (const float*)d_in[14];
  float* out = (float*)d_out;

  const int N = in_sizes[2];          // 100000 nodes
  const int E = in_sizes[1] / 2;      // 1.6M edges
  const int G = out_size / 96;        // 128 graphs
  const int NBK = (N + 255) >> 8;     // coarse buckets (391)
  const int chunk = (E + NSB - 1) / NSB;

  size_t off = 0;
  auto alloc = [&](size_t bytes) {
    void* p = (char*)d_ws + off;
    off += (bytes + 255) & ~(size_t)255;
    return p;
  };
  unsigned short* h_bf = (unsigned short*)alloc((size_t)N * 192 * 2);   // h1, later h2
  unsigned short* o1_bf = (unsigned short*)alloc((size_t)N * 192 * 2);  // layer1 out
  float* o2_f = (float*)alloc((size_t)N * 96 * 4);                      // layer2 out
  float* asrc1 = (float*)alloc((size_t)N * 4 * 4);
  float* adst1 = (float*)alloc((size_t)N * 4 * 4);
  float* asrc2 = (float*)alloc((size_t)N * 4);
  float* adst2 = (float*)alloc((size_t)N * 4);
  unsigned short* W1h = (unsigned short*)alloc((size_t)192 * 128 * 2);
  unsigned short* W1l = (unsigned short*)alloc((size_t)192 * 128 * 2);
  unsigned short* W2h = (unsigned short*)alloc((size_t)96 * 192 * 2);
  unsigned short* W2l = (unsigned short*)alloc((size_t)96 * 192 * 2);
  int* row_off = (int*)alloc((size_t)(N + 1) * 4);
  int* col = (int*)alloc((size_t)(E + N) * 4);
  int* pairs = (int*)alloc((size_t)E * 4);
  int* cntmat = (int*)alloc((size_t)NBK * NSB * 4);
  int* bucket_tot = (int*)alloc((size_t)NBK * 4);
  int* bucket_off = (int*)alloc((size_t)(NBK + 1) * 4);
  float* part = (float*)alloc((size_t)G * 8 * 96 * 4);
  (void)ws_size;

  const int* src = ei;
  const int* dst = ei + E;

  // --- weight conversion (one launch, both layers) ---
  k_convW<<<(128 * 192 + 192 * 96 + 255) / 256, 256, 0, stream>>>(W1, W2, W1h, W1l, W2h, W2l);

  // --- binned CSR build (atomic-free global ordering) ---
  k_hist2<<<NSB, 256, 0, stream>>>(dst, E, chunk, NBK, cntmat);
  k_rowscan<<<NBK, 256, 0, stream>>>(cntmat, bucket_tot);
  k_bscan<<<1, 512, 0, stream>>>(bucket_tot, NBK, bucket_off, row_off, N, E);
  k_scatter2<<<NSB, 256, 0, stream>>>(src, dst, E, chunk, NBK, bucket_off, cntmat, pairs);
  k_bbuild<<<NBK, 256, 0, stream>>>(pairs, bucket_off, N, row_off, col);

  int gblk = (N + 127) / 128;
  int nblk4 = (N + 3) / 4;

  // --- layer 1 ---
  k_gemm_mfma<128, 192, false><<<gblk, 256, 0, stream>>>(x, W1h, W1l, h_bf, N);
  k_coef1<<<nblk4, 256, 0, stream>>>(h_bf, a_src1, a_dst1, asrc1, adst1, N);
  k_agg1<<<nblk4, 256, 0, stream>>>(h_bf, asrc1, adst1, row_off, col, b1, o1_bf, N);

  // --- layer 2 ---
  k_gemm_mfma<192, 96, true><<<gblk, 256, 0, stream>>>(o1_bf, W2h, W2l, h_bf, N);
  k_coef2<<<nblk4, 256, 0, stream>>>(h_bf, a_src2, a_dst2, asrc2, adst2, N);
  k_agg2<<<nblk4, 256, 0, stream>>>(h_bf, asrc2, adst2, row_off, col, b2, o2_f, N);

  // --- pool + MLP ---
  k_pool<<<G * 8, 384, 0, stream>>>(o2_f, batch, N, part);
  k_mlp<<<G, 192, 0, stream>>>(part, batch, N, fc1w, fc1b, fc2w, fc2b, out);
}